// Round 14
// baseline (41.720 us; speedup 1.0000x reference)
//
#include <hip/hip_runtime.h>
#include <hip/hip_bf16.h>
#include <type_traits>

// out = x @ M^T + c, with M = Wo @ Wv_sub (softmax row-sum == 1 collapses attn to v).
#define MROWS 4096   // B*S
#define EDIM  1024

typedef __attribute__((ext_vector_type(8))) __bf16 bf16x8;
typedef __attribute__((ext_vector_type(4))) float f32x4;
typedef __attribute__((ext_vector_type(8))) unsigned short ushort8;
typedef __attribute__((ext_vector_type(4))) unsigned short ushort4v;
typedef __attribute__((ext_vector_type(4))) unsigned int uint4v;

__device__ __forceinline__ unsigned short f2bf(float f) {
    unsigned u = __builtin_bit_cast(unsigned, f);
    u += 0x7FFFu + ((u >> 16) & 1u);   // round-to-nearest-even
    return (unsigned short)(u >> 16);
}

// packed f32x2 -> bf16x2 (RNE), single VALU op
__device__ __forceinline__ unsigned cvt_pk_bf16(float a, float b) {
    unsigned r;
    asm("v_cvt_pk_bf16_f32 %0, %1, %2" : "=v"(r) : "v"(a), "v"(b));
    return r;
}

__device__ __forceinline__ void async_load16(const void* g, void* l) {
    __builtin_amdgcn_global_load_lds(
        (const __attribute__((address_space(1))) void*)g,
        (__attribute__((address_space(3))) void*)l, 16, 0, 0);
}

template<int N> __device__ __forceinline__ void wait_vmcnt() {
    if constexpr (N == 0)       asm volatile("s_waitcnt vmcnt(0)" ::: "memory");
    else if constexpr (N == 4)  asm volatile("s_waitcnt vmcnt(4)" ::: "memory");
    else if constexpr (N == 6)  asm volatile("s_waitcnt vmcnt(6)" ::: "memory");
    else if constexpr (N == 8)  asm volatile("s_waitcnt vmcnt(8)" ::: "memory");
    else if constexpr (N == 12) asm volatile("s_waitcnt vmcnt(12)" ::: "memory");
    else static_assert(N < 0, "unsupported vmcnt literal");
}

// cast 8 consecutive f32 -> bf16 at flat ushort8 index i
__device__ __forceinline__ void cast8(const float* __restrict__ in,
                                      unsigned short* __restrict__ out, int i) {
    const float4* p = (const float4*)in + (size_t)i * 2;
    float4 a = p[0], b = p[1];
    ushort8 r;
    r[0] = f2bf(a.x); r[1] = f2bf(a.y); r[2] = f2bf(a.z); r[3] = f2bf(a.w);
    r[4] = f2bf(b.x); r[5] = f2bf(b.y); r[6] = f2bf(b.z); r[7] = f2bf(b.w);
    *((ushort8*)out + i) = r;
}

// ---------------- NBUF-buffer counted-vmcnt + T2-swizzled bf16 MFMA GEMM -------
// (unchanged from r12 — used by gemm1) C[m,n] = sum_k A[m,k]*B[n,k].
template<bool BIAS, typename OUT_T, int MD, int ND, int KD,
         int BM, int BN, int BK, int NWM, int NWN, int NBUF>
__device__ __forceinline__ void gemm_bt_body(
    const unsigned short* __restrict__ A, const unsigned short* __restrict__ B,
    OUT_T* __restrict__ C, const float* __restrict__ bias, int id,
    unsigned short* sm)
{
    constexpr int THREADS = NWM * NWN * 64;
    constexpr int NBM = MD / BM, NBN = ND / BN, NWG = NBM * NBN;
    constexpr int CPX = NWG / 8;
    constexpr int WTM = BM / NWM, WTN = BN / NWN;
    constexpr int AM = WTM / 16, AN = WTN / 16;
    constexpr int CHUNKS = BK / 8;
    constexpr int RPP = THREADS / CHUNKS;
    constexpr int TILE = (BM + BN) * BK;
    constexpr int L = BM / RPP + BN / RPP;
    constexpr int NIT = KD / BK;
    constexpr int AHEAD = NBUF - 1;
    static_assert(RPP % 8 == 0, "row-phase must be p-invariant for source swizzle");
    static_assert(CHUNKS == 8, "XOR swizzle assumes 8 chunks per row");

    const int t = threadIdx.x;
    const int swz = (id & 7) * CPX + (id >> 3);
    const int bm = swz / NBN, bn = swz % NBN;   // bm-chunk per XCD

    const int lane = t & 63, wave = t >> 6;
    const int wr = wave / NWN, wc = wave % NWN;

    const int rsub = t / CHUNKS;
    const int kb   = (t % CHUNKS) * 8;
    const int kbs  = kb ^ ((rsub & 7) * 8);

    const unsigned short* Ag = A + (size_t)(bm * BM + rsub) * KD + kbs;
    const unsigned short* Bg = B + (size_t)(bn * BN + rsub) * KD + kbs;

    f32x4 acc[AM][AN] = {};

    auto stage = [&](int buf, int k0) {
        unsigned short* As = sm + buf * TILE;
        unsigned short* Bs = As + BM * BK;
        #pragma unroll
        for (int p = 0; p < BM / RPP; ++p)
            async_load16(Ag + (size_t)(p * RPP) * KD + k0, &As[(rsub + p * RPP) * BK + kb]);
        #pragma unroll
        for (int p = 0; p < BN / RPP; ++p)
            async_load16(Bg + (size_t)(p * RPP) * KD + k0, &Bs[(rsub + p * RPP) * BK + kb]);
    };

    auto compute = [&](int buf) {
        const unsigned short* As = sm + buf * TILE;
        const unsigned short* Bs = As + BM * BK;
        #pragma unroll
        for (int ks = 0; ks < BK / 32; ++ks) {
            bf16x8 a[AM], b[AN];
            #pragma unroll
            for (int mi = 0; mi < AM; ++mi) {
                const int ar = wr * WTM + mi * 16 + (lane & 15);
                const int cg = ks * 4 + (lane >> 4);
                a[mi] = *(const bf16x8*)&As[ar * BK + ((cg ^ (ar & 7)) * 8)];
            }
            #pragma unroll
            for (int ni = 0; ni < AN; ++ni) {
                const int br = wc * WTN + ni * 16 + (lane & 15);
                const int cg = ks * 4 + (lane >> 4);
                b[ni] = *(const bf16x8*)&Bs[br * BK + ((cg ^ (br & 7)) * 8)];
            }
            #pragma unroll
            for (int mi = 0; mi < AM; ++mi)
                #pragma unroll
                for (int ni = 0; ni < AN; ++ni)
                    acc[mi][ni] = __builtin_amdgcn_mfma_f32_16x16x32_bf16(
                        b[ni], a[mi], acc[mi][ni], 0, 0, 0);
        }
    };

    #pragma unroll
    for (int p = 0; p < AHEAD; ++p) stage(p, p * BK);

    for (int it = 0; it < NIT; ++it) {
        __builtin_amdgcn_s_barrier();
        if (it + AHEAD < NIT) {
            stage((it + AHEAD) % NBUF, (it + AHEAD) * BK);
            wait_vmcnt<AHEAD * L>();
        } else if (it + 1 < NIT) {
            wait_vmcnt<L>();
        } else {
            wait_vmcnt<0>();
        }
        __builtin_amdgcn_s_barrier();
        compute(it % NBUF);
    }

    const int mrow  = bm * BM + wr * WTM + (lane & 15);
    const int ncol0 = bn * BN + wc * WTN + (lane >> 4) * 4;
    #pragma unroll
    for (int mi = 0; mi < AM; ++mi) {
        const int row = mrow + mi * 16;
        #pragma unroll
        for (int ni = 0; ni < AN; ++ni) {
            const int col = ncol0 + ni * 16;
            f32x4 v = acc[mi][ni];
            if constexpr (BIAS) {
                const f32x4 bv = *(const f32x4*)&bias[col];
                v += bv;
            }
            if constexpr (std::is_same<OUT_T, float>::value) {
                __builtin_nontemporal_store(v, (f32x4*)&C[(size_t)row * ND + col]);
            } else {
                ushort4v r;
                r[0] = f2bf(v[0]); r[1] = f2bf(v[1]);
                r[2] = f2bf(v[2]); r[3] = f2bf(v[3]);
                *(ushort4v*)&C[(size_t)row * ND + col] = r;
            }
        }
    }
}

// ---------------- K1: weight prep ----------------
// blocks [0,256):   WvT[e,k] = bf16(Wqkv[vrow(k), e])  (16x16 tiles of 64x64)
// blocks [256,768): Wo -> bf16
// blocks [768,784): c[i] = bo[i] + sum_k Wo[i,k]*bqkv[vrow(k)]
__global__ __launch_bounds__(256) void prep_w(
    const float* __restrict__ Wqkv, const float* __restrict__ bqkv,
    const float* __restrict__ Wo, const float* __restrict__ bo,
    unsigned short* __restrict__ WvT, unsigned short* __restrict__ wo_bf,
    float* __restrict__ c)
{
    const int blk = blockIdx.x;
    const int t = threadIdx.x;
    if (blk < 256) {                        // ---- build WvT ----
        __shared__ unsigned short tile[64][65];
        const int eBase = (blk & 15) * 64, kBase = (blk >> 4) * 64;
        const int tx = t & 63, ty = t >> 6;
        #pragma unroll
        for (int r = ty; r < 64; r += 4) {
            int k = kBase + r;
            int j = ((k >> 6) * 192) + 128 + (k & 63);   // vrow(k)
            tile[r][tx] = f2bf(Wqkv[(size_t)j * EDIM + eBase + tx]);
        }
        __syncthreads();
        #pragma unroll
        for (int r = ty; r < 64; r += 4)
            WvT[(size_t)(eBase + r) * EDIM + kBase + tx] = tile[tx][r];
    } else if (blk < 768) {                 // ---- cast Wo ----
        cast8(Wo, wo_bf, (blk - 256) * 256 + t);
    } else {                                // ---- fused bias c ----
        const int b = blk - 768;            // 0..15
        const int wave = t >> 6, lane = t & 63;
        for (int r = 0; r < 16; ++r) {
            int row = b * 64 + wave * 16 + r;
            float s = 0.f;
            #pragma unroll
            for (int kk = 0; kk < 16; ++kk) {
                int k = kk * 64 + lane;
                int j = kk * 192 + 128 + lane;   // vrow(k)
                s += Wo[(size_t)row * EDIM + k] * bqkv[j];
            }
            #pragma unroll
            for (int off = 32; off > 0; off >>= 1) s += __shfl_down(s, off);
            if (lane == 0) c[row] = s + bo[row];
        }
    }
}

// ---------------- K2: gemm1 (M = Wo @ Wv_sub) ----------------
// 256 blocks (one per CU), 64x64 tiles, NBUF=3 counted-vmcnt.
__global__ __launch_bounds__(256, 2) void gemm1k(
    const unsigned short* __restrict__ wo_bf, const unsigned short* __restrict__ wvt,
    unsigned short* __restrict__ m_bf)
{
    __shared__ unsigned short smem[3 * (64 + 64) * 64];   // 48 KB
    gemm_bt_body<false, unsigned short, EDIM, EDIM, EDIM, 64, 64, 64, 2, 2, 3>(
        wo_bf, wvt, m_bf, nullptr, blockIdx.x, smem);
}

// ---------------- K3: out = x(f32) @ M^T + c — fused-cast GEMM (T14) ----------
// A = x read DIRECTLY in f32: global->reg (4x dwordx4, issued 1 iter ahead),
// v_cvt_pk_bf16_f32, ds_write_b128 into write-side-swizzled LDS. B = m_bf via
// global_load_lds + source swizzle. Eliminates the x_bf 16MB round-trip.
// 128x128 tile, 8 waves (2x4, acc[4][2]), NBUF=2, 64 KB LDS, grid 256,
// bm-chunk XCD swizzle (2MB f32 x-chunk + 2MB M per XCD L2-resident).
__global__ __launch_bounds__(512, 2) void gemm2f(
    const float* __restrict__ x, const unsigned short* __restrict__ Bm,
    float* __restrict__ out, const float* __restrict__ cvec)
{
    constexpr int BM = 128, BN = 128, BK = 64, NIT = EDIM / BK, NBUF = 2;
    constexpr int NBM = MROWS / BM, NBN = EDIM / BN, NWG = NBM * NBN;
    constexpr int CPX = NWG / 8;
    constexpr int TILE = (BM + BN) * BK;
    __shared__ unsigned short sm[NBUF * TILE];             // 64 KB

    const int t = threadIdx.x;
    const int id = blockIdx.x;
    const int swz = (id & 7) * CPX + (id >> 3);
    const int bm = swz / NBN, bn = swz % NBN;              // bm-chunk per XCD

    const int lane = t & 63, wave = t >> 6;
    const int wr = wave >> 2, wc = wave & 3;               // 2x4 wave grid

    // A staging: thread owns row rowA, 16 floats at k = j*16 (2 swizzled chunks)
    const int rowA = t >> 2, j = t & 3;
    const float* Ag = x + (size_t)(bm * BM + rowA) * EDIM + j * 16;
    const int c0 = ((2 * j)     ^ (rowA & 7)) * 8;         // write-side swizzle
    const int c1 = ((2 * j + 1) ^ (rowA & 7)) * 8;

    // B staging: global_load_lds, source-swizzled (as r12)
    const int rsubB = t >> 3, kbB = (t & 7) * 8;
    const int kbsB = kbB ^ ((rsubB & 7) * 8);
    const unsigned short* Bg = Bm + (size_t)(bn * BN + rsubB) * EDIM + kbsB;

    f32x4 acc[4][2] = {};
    float4 L0, L1, L2, L3;                                  // A f32 in flight

    auto issueA = [&](int k0) {
        const float4* p = (const float4*)(Ag + k0);
        L0 = p[0]; L1 = p[1]; L2 = p[2]; L3 = p[3];
    };
    auto stageB = [&](int buf, int k0) {
        unsigned short* Bs = sm + buf * TILE + BM * BK;
        #pragma unroll
        for (int p = 0; p < 2; ++p)
            async_load16(Bg + (size_t)(p * 64) * EDIM + k0, &Bs[(rsubB + p * 64) * BK + kbB]);
    };
    auto writeA = [&](int buf) {                            // cvt + 2x b128 store
        unsigned short* As = sm + buf * TILE;
        uint4v w0, w1;
        w0[0] = cvt_pk_bf16(L0.x, L0.y); w0[1] = cvt_pk_bf16(L0.z, L0.w);
        w0[2] = cvt_pk_bf16(L1.x, L1.y); w0[3] = cvt_pk_bf16(L1.z, L1.w);
        w1[0] = cvt_pk_bf16(L2.x, L2.y); w1[1] = cvt_pk_bf16(L2.z, L2.w);
        w1[2] = cvt_pk_bf16(L3.x, L3.y); w1[3] = cvt_pk_bf16(L3.z, L3.w);
        *(uint4v*)&As[rowA * BK + c0] = w0;
        *(uint4v*)&As[rowA * BK + c1] = w1;
    };
    auto compute = [&](int buf) {
        const unsigned short* As = sm + buf * TILE;
        const unsigned short* Bs = As + BM * BK;
        #pragma unroll
        for (int ks = 0; ks < 2; ++ks) {
            bf16x8 a[4], b[2];
            #pragma unroll
            for (int mi = 0; mi < 4; ++mi) {
                const int ar = wr * 64 + mi * 16 + (lane & 15);
                const int cg = ks * 4 + (lane >> 4);
                a[mi] = *(const bf16x8*)&As[ar * BK + ((cg ^ (ar & 7)) * 8)];
            }
            #pragma unroll
            for (int ni = 0; ni < 2; ++ni) {
                const int br = wc * 32 + ni * 16 + (lane & 15);
                const int cg = ks * 4 + (lane >> 4);
                b[ni] = *(const bf16x8*)&Bs[br * BK + ((cg ^ (br & 7)) * 8)];
            }
            #pragma unroll
            for (int mi = 0; mi < 4; ++mi)
                #pragma unroll
                for (int ni = 0; ni < 2; ++ni)
                    acc[mi][ni] = __builtin_amdgcn_mfma_f32_16x16x32_bf16(
                        b[ni], a[mi], acc[mi][ni], 0, 0, 0);
        }
    };

    // prologue: A(0) regs + B(0) lds in flight
    issueA(0);
    stageB(0, 0);

    for (int it = 0; it < NIT; ++it) {
        __builtin_amdgcn_s_barrier();       // compute(it-1) retired -> buffers free
        writeA(it & 1);                     // compiler auto-waits vmcnt for L regs
        if (it + 1 < NIT) {
            issueA((it + 1) * BK);          // 4 reg loads (A, f32)
            stageB((it & 1) ^ 1, (it + 1) * BK);   // 2 gload_lds (B)
            wait_vmcnt<6>();                // B(it) landed; 6 newest may fly
        } else {
            wait_vmcnt<0>();
        }
        asm volatile("s_waitcnt lgkmcnt(0)" ::: "memory");  // my ds_writes done
        __builtin_amdgcn_s_barrier();       // everyone's tile-it in LDS
        compute(it & 1);
    }

    // Swapped C/D layout -> float4 stores, consecutive in n.
    const int mrow  = bm * BM + wr * 64 + (lane & 15);
    const int ncol0 = bn * BN + wc * 32 + (lane >> 4) * 4;
    #pragma unroll
    for (int mi = 0; mi < 4; ++mi) {
        const int row = mrow + mi * 16;
        #pragma unroll
        for (int ni = 0; ni < 2; ++ni) {
            const int col = ncol0 + ni * 16;
            f32x4 v = acc[mi][ni];
            const f32x4 bv = *(const f32x4*)&cvec[col];
            v += bv;
            __builtin_nontemporal_store(v, (f32x4*)&out[(size_t)row * EDIM + col]);
        }
    }
}

extern "C" void kernel_launch(void* const* d_in, const int* in_sizes, int n_in,
                              void* d_out, int out_size, void* d_ws, size_t ws_size,
                              hipStream_t stream) {
    const float* x    = (const float*)d_in[0];   // (2,2048,1024)
    const float* Wqkv = (const float*)d_in[1];   // (3072,1024)
    const float* bqkv = (const float*)d_in[2];   // (3072,)
    const float* Wo   = (const float*)d_in[3];   // (1024,1024)
    const float* bo   = (const float*)d_in[4];   // (1024,)
    float* out = (float*)d_out;                  // (2,2048,1024) f32

    char* ws = (char*)d_ws;
    unsigned short* wvt   = (unsigned short*)(ws);                       // 2 MB
    unsigned short* wo_bf = (unsigned short*)(ws + 2u * 1024 * 1024);    // 2 MB
    unsigned short* m_bf  = (unsigned short*)(ws + 4u * 1024 * 1024);    // 2 MB
    float*          cvec  = (float*)(ws + 6u * 1024 * 1024);             // 4 KB

    // K1: weight prep (WvT gather/transpose, Wo cast, fused bias c)
    prep_w<<<784, 256, 0, stream>>>(Wqkv, bqkv, Wo, bo, wvt, wo_bf, cvec);
    // K2: M = Wo @ Wv_sub (256 blocks, 64x64, NBUF=3)
    gemm1k<<<256, 256, 0, stream>>>(wo_bf, wvt, m_bf);
    // K3: out = x(f32) @ M^T + c — fused cast, no x_bf intermediate
    gemm2f<<<256, 512, 0, stream>>>(x, m_bf, out, cvec);
}

// Round 15
// 40.536 us; speedup vs baseline: 1.0292x; 1.0292x over previous
//
#include <hip/hip_runtime.h>
#include <hip/hip_bf16.h>
#include <type_traits>

// out = x @ M^T + c, with M = Wo @ Wv_sub (softmax row-sum == 1 collapses attn to v).
#define MROWS 4096   // B*S
#define EDIM  1024

typedef __attribute__((ext_vector_type(8))) __bf16 bf16x8;
typedef __attribute__((ext_vector_type(4))) float f32x4;
typedef __attribute__((ext_vector_type(8))) unsigned short ushort8;
typedef __attribute__((ext_vector_type(4))) unsigned short ushort4v;

__device__ __forceinline__ unsigned short f2bf(float f) {
    unsigned u = __builtin_bit_cast(unsigned, f);
    u += 0x7FFFu + ((u >> 16) & 1u);   // round-to-nearest-even
    return (unsigned short)(u >> 16);
}

__device__ __forceinline__ void async_load16(const void* g, void* l) {
    __builtin_amdgcn_global_load_lds(
        (const __attribute__((address_space(1))) void*)g,
        (__attribute__((address_space(3))) void*)l, 16, 0, 0);
}

template<int N> __device__ __forceinline__ void wait_vmcnt() {
    if constexpr (N == 0)       asm volatile("s_waitcnt vmcnt(0)" ::: "memory");
    else if constexpr (N == 4)  asm volatile("s_waitcnt vmcnt(4)" ::: "memory");
    else if constexpr (N == 6)  asm volatile("s_waitcnt vmcnt(6)" ::: "memory");
    else if constexpr (N == 8)  asm volatile("s_waitcnt vmcnt(8)" ::: "memory");
    else if constexpr (N == 12) asm volatile("s_waitcnt vmcnt(12)" ::: "memory");
    else static_assert(N < 0, "unsupported vmcnt literal");
}

// cast 8 consecutive f32 -> bf16 at flat ushort8 index i
__device__ __forceinline__ void cast8(const float* __restrict__ in,
                                      unsigned short* __restrict__ out, int i) {
    const float4* p = (const float4*)in + (size_t)i * 2;
    float4 a = p[0], b = p[1];
    ushort8 r;
    r[0] = f2bf(a.x); r[1] = f2bf(a.y); r[2] = f2bf(a.z); r[3] = f2bf(a.w);
    r[4] = f2bf(b.x); r[5] = f2bf(b.y); r[6] = f2bf(b.z); r[7] = f2bf(b.w);
    *((ushort8*)out + i) = r;
}

// ---------------- NBUF-buffer counted-vmcnt + T2-swizzled bf16 MFMA GEMM -------
// C[m,n] = sum_k A[m,k]*B[n,k] (+bias[n]). BMxBN tile, BK=64, NWM x NWN waves.
// T3+T4: NBUF-1 tiles in flight, raw s_barrier, counted vmcnt (never 0 in
// steady state). T2 (rule #21): linear LDS dest + inverse-swizzled global
// source + same XOR on ds_read.
// OPERAND-SWAP EPILOGUE: mfma(b,a,acc) transposes the C/D mapping so the reg
// index walks CONSECUTIVE COLUMNS -> one float4/ushort4 store per fragment.
// XCD swizzle, bm-CHUNK ownership: bm = swz/NBN (each XCD owns a contiguous
// bm-row chunk; its A-panel AND the full B matrix fit its private L2).
// sm must hold NBUF*(BM+BN)*BK ushorts.
template<bool BIAS, typename OUT_T, int MD, int ND, int KD,
         int BM, int BN, int BK, int NWM, int NWN, int NBUF>
__device__ __forceinline__ void gemm_bt_body(
    const unsigned short* __restrict__ A, const unsigned short* __restrict__ B,
    OUT_T* __restrict__ C, const float* __restrict__ bias, int id,
    unsigned short* sm)
{
    constexpr int THREADS = NWM * NWN * 64;
    constexpr int NBM = MD / BM, NBN = ND / BN, NWG = NBM * NBN;
    constexpr int CPX = NWG / 8;
    constexpr int WTM = BM / NWM, WTN = BN / NWN;
    constexpr int AM = WTM / 16, AN = WTN / 16;
    constexpr int CHUNKS = BK / 8;
    constexpr int RPP = THREADS / CHUNKS;
    constexpr int TILE = (BM + BN) * BK;
    constexpr int L = BM / RPP + BN / RPP;
    constexpr int NIT = KD / BK;
    constexpr int AHEAD = NBUF - 1;
    static_assert(RPP % 8 == 0, "row-phase must be p-invariant for source swizzle");
    static_assert(CHUNKS == 8, "XOR swizzle assumes 8 chunks per row");

    const int t = threadIdx.x;
    const int swz = (id & 7) * CPX + (id >> 3);
    const int bm = swz / NBN, bn = swz % NBN;   // bm-chunk per XCD

    const int lane = t & 63, wave = t >> 6;
    const int wr = wave / NWN, wc = wave % NWN;

    const int rsub = t / CHUNKS;
    const int kb   = (t % CHUNKS) * 8;
    const int kbs  = kb ^ ((rsub & 7) * 8);

    const unsigned short* Ag = A + (size_t)(bm * BM + rsub) * KD + kbs;
    const unsigned short* Bg = B + (size_t)(bn * BN + rsub) * KD + kbs;

    f32x4 acc[AM][AN] = {};

    auto stage = [&](int buf, int k0) {
        unsigned short* As = sm + buf * TILE;
        unsigned short* Bs = As + BM * BK;
        #pragma unroll
        for (int p = 0; p < BM / RPP; ++p)
            async_load16(Ag + (size_t)(p * RPP) * KD + k0, &As[(rsub + p * RPP) * BK + kb]);
        #pragma unroll
        for (int p = 0; p < BN / RPP; ++p)
            async_load16(Bg + (size_t)(p * RPP) * KD + k0, &Bs[(rsub + p * RPP) * BK + kb]);
    };

    auto compute = [&](int buf) {
        const unsigned short* As = sm + buf * TILE;
        const unsigned short* Bs = As + BM * BK;
        #pragma unroll
        for (int ks = 0; ks < BK / 32; ++ks) {
            bf16x8 a[AM], b[AN];
            #pragma unroll
            for (int mi = 0; mi < AM; ++mi) {
                const int ar = wr * WTM + mi * 16 + (lane & 15);
                const int cg = ks * 4 + (lane >> 4);
                a[mi] = *(const bf16x8*)&As[ar * BK + ((cg ^ (ar & 7)) * 8)];
            }
            #pragma unroll
            for (int ni = 0; ni < AN; ++ni) {
                const int br = wc * WTN + ni * 16 + (lane & 15);
                const int cg = ks * 4 + (lane >> 4);
                b[ni] = *(const bf16x8*)&Bs[br * BK + ((cg ^ (br & 7)) * 8)];
            }
            #pragma unroll
            for (int mi = 0; mi < AM; ++mi)
                #pragma unroll
                for (int ni = 0; ni < AN; ++ni)
                    acc[mi][ni] = __builtin_amdgcn_mfma_f32_16x16x32_bf16(
                        b[ni], a[mi], acc[mi][ni], 0, 0, 0);
        }
    };

    #pragma unroll
    for (int p = 0; p < AHEAD; ++p) stage(p, p * BK);

    for (int it = 0; it < NIT; ++it) {
        __builtin_amdgcn_s_barrier();
        if (it + AHEAD < NIT) {
            stage((it + AHEAD) % NBUF, (it + AHEAD) * BK);
            wait_vmcnt<AHEAD * L>();
        } else if (it + 1 < NIT) {
            wait_vmcnt<L>();
        } else {
            wait_vmcnt<0>();
        }
        __builtin_amdgcn_s_barrier();
        compute(it % NBUF);
    }

    const int mrow  = bm * BM + wr * WTM + (lane & 15);
    const int ncol0 = bn * BN + wc * WTN + (lane >> 4) * 4;
    #pragma unroll
    for (int mi = 0; mi < AM; ++mi) {
        const int row = mrow + mi * 16;
        #pragma unroll
        for (int ni = 0; ni < AN; ++ni) {
            const int col = ncol0 + ni * 16;
            f32x4 v = acc[mi][ni];
            if constexpr (BIAS) {
                const f32x4 bv = *(const f32x4*)&bias[col];
                v += bv;
            }
            if constexpr (std::is_same<OUT_T, float>::value) {
                __builtin_nontemporal_store(v, (f32x4*)&C[(size_t)row * ND + col]);
            } else {
                ushort4v r;
                r[0] = f2bf(v[0]); r[1] = f2bf(v[1]);
                r[2] = f2bf(v[2]); r[3] = f2bf(v[3]);
                *(ushort4v*)&C[(size_t)row * ND + col] = r;
            }
        }
    }
}

// ---------------- K1: weight prep ----------------
// blocks [0,256):   WvT[e,k] = bf16(Wqkv[vrow(k), e])  (16x16 tiles of 64x64)
// blocks [256,768): Wo -> bf16
// blocks [768,784): c[i] = bo[i] + sum_k Wo[i,k]*bqkv[vrow(k)]
__global__ __launch_bounds__(256) void prep_w(
    const float* __restrict__ Wqkv, const float* __restrict__ bqkv,
    const float* __restrict__ Wo, const float* __restrict__ bo,
    unsigned short* __restrict__ WvT, unsigned short* __restrict__ wo_bf,
    float* __restrict__ c)
{
    const int blk = blockIdx.x;
    const int t = threadIdx.x;
    if (blk < 256) {                        // ---- build WvT ----
        __shared__ unsigned short tile[64][65];
        const int eBase = (blk & 15) * 64, kBase = (blk >> 4) * 64;
        const int tx = t & 63, ty = t >> 6;
        #pragma unroll
        for (int r = ty; r < 64; r += 4) {
            int k = kBase + r;
            int j = ((k >> 6) * 192) + 128 + (k & 63);   // vrow(k)
            tile[r][tx] = f2bf(Wqkv[(size_t)j * EDIM + eBase + tx]);
        }
        __syncthreads();
        #pragma unroll
        for (int r = ty; r < 64; r += 4)
            WvT[(size_t)(eBase + r) * EDIM + kBase + tx] = tile[tx][r];
    } else if (blk < 768) {                 // ---- cast Wo ----
        cast8(Wo, wo_bf, (blk - 256) * 256 + t);
    } else {                                // ---- fused bias c ----
        const int b = blk - 768;            // 0..15
        const int wave = t >> 6, lane = t & 63;
        for (int r = 0; r < 16; ++r) {
            int row = b * 64 + wave * 16 + r;
            float s = 0.f;
            #pragma unroll
            for (int kk = 0; kk < 16; ++kk) {
                int k = kk * 64 + lane;
                int j = kk * 192 + 128 + lane;   // vrow(k)
                s += Wo[(size_t)row * EDIM + k] * bqkv[j];
            }
            #pragma unroll
            for (int off = 32; off > 0; off >>= 1) s += __shfl_down(s, off);
            if (lane == 0) c[row] = s + bo[row];
        }
    }
}

// ---------------- K2: gemm1 (M = Wo @ Wv_sub) co-dispatched with cast_x ----------------
// blocks [0,256):    M GEMM, 64x64 tiles (one block per CU), 3-buf counted-vmcnt
// blocks [256,2304): x -> bf16 (4M elems, 2048 elems/block)
__global__ __launch_bounds__(256, 2) void gemm1_castx(
    const unsigned short* __restrict__ wo_bf, const unsigned short* __restrict__ wvt,
    unsigned short* __restrict__ m_bf,
    const float* __restrict__ x, unsigned short* __restrict__ x_bf)
{
    __shared__ unsigned short smem[3 * (64 + 64) * 64];   // 48 KB
    const int blk = blockIdx.x;
    if (blk < 256) {
        gemm_bt_body<false, unsigned short, EDIM, EDIM, EDIM, 64, 64, 64, 2, 2, 3>(
            wo_bf, wvt, m_bf, nullptr, blk, smem);
    } else {
        cast8(x, x_bf, (blk - 256) * 256 + threadIdx.x);
    }
}

// ---------------- K3: out = x @ M^T + c ----------------
// 128x128 tiles, 8 waves (2x4 grid, acc[4][2]), 2-buffer counted-vmcnt
// (steady vmcnt(4)), 64 KB LDS, grid 256. T2 swizzle + float4 epilogue.
// bm-chunk XCD swizzle: each XCD's 1 MB x-panel + full 2 MB M L2-resident.
__global__ __launch_bounds__(512, 2) void gemm2(
    const unsigned short* __restrict__ x_bf, const unsigned short* __restrict__ m_bf,
    float* __restrict__ out, const float* __restrict__ cvec)
{
    __shared__ unsigned short smem[2 * (128 + 128) * 64];  // 64 KB
    gemm_bt_body<true, float, MROWS, EDIM, EDIM, 128, 128, 64, 2, 4, 2>(
        x_bf, m_bf, out, cvec, blockIdx.x, smem);
}

extern "C" void kernel_launch(void* const* d_in, const int* in_sizes, int n_in,
                              void* d_out, int out_size, void* d_ws, size_t ws_size,
                              hipStream_t stream) {
    const float* x    = (const float*)d_in[0];   // (2,2048,1024)
    const float* Wqkv = (const float*)d_in[1];   // (3072,1024)
    const float* bqkv = (const float*)d_in[2];   // (3072,)
    const float* Wo   = (const float*)d_in[3];   // (1024,1024)
    const float* bo   = (const float*)d_in[4];   // (1024,)
    float* out = (float*)d_out;                  // (2,2048,1024) f32

    char* ws = (char*)d_ws;
    unsigned short* x_bf  = (unsigned short*)(ws);                       // 8 MB
    unsigned short* wvt   = (unsigned short*)(ws + 8u  * 1024 * 1024);   // 2 MB
    unsigned short* wo_bf = (unsigned short*)(ws + 10u * 1024 * 1024);   // 2 MB
    unsigned short* m_bf  = (unsigned short*)(ws + 12u * 1024 * 1024);   // 2 MB
    float*          cvec  = (float*)(ws + 14u * 1024 * 1024);            // 4 KB

    // K1: weight prep (WvT gather/transpose, Wo cast, fused bias c)
    prep_w<<<784, 256, 0, stream>>>(Wqkv, bqkv, Wo, bo, wvt, wo_bf, cvec);
    // K2: M = Wo @ Wv_sub (256 blocks, 64x64, NBUF=3)  ||  x -> bf16 (2048 blocks)
    gemm1_castx<<<2304, 256, 0, stream>>>(wo_bf, wvt, m_bf, x, x_bf);
    // K3: out = x @ M^T + c (128x128, 8 waves, counted-vmcnt, T2, bm-chunk swizzle)
    gemm2<<<256, 512, 0, stream>>>(x_bf, m_bf, out, cvec);
}

// Round 16
// 39.965 us; speedup vs baseline: 1.0439x; 1.0143x over previous
//
#include <hip/hip_runtime.h>
#include <hip/hip_bf16.h>
#include <type_traits>

// out = x @ M^T + c, with M = Wo @ Wv_sub (softmax row-sum == 1 collapses attn to v).
#define MROWS 4096   // B*S
#define EDIM  1024

typedef __attribute__((ext_vector_type(8))) __bf16 bf16x8;
typedef __attribute__((ext_vector_type(4))) float f32x4;
typedef __attribute__((ext_vector_type(8))) unsigned short ushort8;
typedef __attribute__((ext_vector_type(4))) unsigned short ushort4v;

__device__ __forceinline__ unsigned short f2bf(float f) {
    unsigned u = __builtin_bit_cast(unsigned, f);
    u += 0x7FFFu + ((u >> 16) & 1u);   // round-to-nearest-even
    return (unsigned short)(u >> 16);
}

__device__ __forceinline__ void async_load16(const void* g, void* l) {
    __builtin_amdgcn_global_load_lds(
        (const __attribute__((address_space(1))) void*)g,
        (__attribute__((address_space(3))) void*)l, 16, 0, 0);
}

template<int N> __device__ __forceinline__ void wait_vmcnt() {
    if constexpr (N == 0)       asm volatile("s_waitcnt vmcnt(0)" ::: "memory");
    else if constexpr (N == 4)  asm volatile("s_waitcnt vmcnt(4)" ::: "memory");
    else if constexpr (N == 6)  asm volatile("s_waitcnt vmcnt(6)" ::: "memory");
    else if constexpr (N == 8)  asm volatile("s_waitcnt vmcnt(8)" ::: "memory");
    else if constexpr (N == 12) asm volatile("s_waitcnt vmcnt(12)" ::: "memory");
    else static_assert(N < 0, "unsupported vmcnt literal");
}

// cast 8 consecutive f32 -> bf16 at flat ushort8 index i
__device__ __forceinline__ void cast8(const float* __restrict__ in,
                                      unsigned short* __restrict__ out, int i) {
    const float4* p = (const float4*)in + (size_t)i * 2;
    float4 a = p[0], b = p[1];
    ushort8 r;
    r[0] = f2bf(a.x); r[1] = f2bf(a.y); r[2] = f2bf(a.z); r[3] = f2bf(a.w);
    r[4] = f2bf(b.x); r[5] = f2bf(b.y); r[6] = f2bf(b.z); r[7] = f2bf(b.w);
    *((ushort8*)out + i) = r;
}

// ---------------- NBUF-buffer counted-vmcnt + T2-swizzled bf16 MFMA GEMM -------
// C[m,n] = sum_k A[m,k]*B[n,k] (+bias[n]). BMxBN tile, BK=64, NWM x NWN waves.
// T3+T4: NBUF-1 tiles in flight, raw s_barrier, counted vmcnt (never 0 in
// steady state). T2 (rule #21): linear LDS dest + inverse-swizzled global
// source + same XOR on ds_read.
// OPERAND-SWAP EPILOGUE: mfma(b,a,acc) transposes the C/D mapping so the reg
// index walks CONSECUTIVE COLUMNS -> one float4/ushort4 store per fragment.
// XCD swizzle, bm-CHUNK ownership: bm = swz/NBN (each XCD owns a contiguous
// bm-row chunk; its A-panel AND the full B matrix fit its private L2).
// sm must hold NBUF*(BM+BN)*BK ushorts.
template<bool BIAS, typename OUT_T, int MD, int ND, int KD,
         int BM, int BN, int BK, int NWM, int NWN, int NBUF>
__device__ __forceinline__ void gemm_bt_body(
    const unsigned short* __restrict__ A, const unsigned short* __restrict__ B,
    OUT_T* __restrict__ C, const float* __restrict__ bias, int id,
    unsigned short* sm)
{
    constexpr int THREADS = NWM * NWN * 64;
    constexpr int NBM = MD / BM, NBN = ND / BN, NWG = NBM * NBN;
    constexpr int CPX = NWG / 8;
    constexpr int WTM = BM / NWM, WTN = BN / NWN;
    constexpr int AM = WTM / 16, AN = WTN / 16;
    constexpr int CHUNKS = BK / 8;
    constexpr int RPP = THREADS / CHUNKS;
    constexpr int TILE = (BM + BN) * BK;
    constexpr int L = BM / RPP + BN / RPP;
    constexpr int NIT = KD / BK;
    constexpr int AHEAD = NBUF - 1;
    static_assert(RPP % 8 == 0, "row-phase must be p-invariant for source swizzle");
    static_assert(CHUNKS == 8, "XOR swizzle assumes 8 chunks per row");

    const int t = threadIdx.x;
    const int swz = (id & 7) * CPX + (id >> 3);
    const int bm = swz / NBN, bn = swz % NBN;   // bm-chunk per XCD

    const int lane = t & 63, wave = t >> 6;
    const int wr = wave / NWN, wc = wave % NWN;

    const int rsub = t / CHUNKS;
    const int kb   = (t % CHUNKS) * 8;
    const int kbs  = kb ^ ((rsub & 7) * 8);

    const unsigned short* Ag = A + (size_t)(bm * BM + rsub) * KD + kbs;
    const unsigned short* Bg = B + (size_t)(bn * BN + rsub) * KD + kbs;

    f32x4 acc[AM][AN] = {};

    auto stage = [&](int buf, int k0) {
        unsigned short* As = sm + buf * TILE;
        unsigned short* Bs = As + BM * BK;
        #pragma unroll
        for (int p = 0; p < BM / RPP; ++p)
            async_load16(Ag + (size_t)(p * RPP) * KD + k0, &As[(rsub + p * RPP) * BK + kb]);
        #pragma unroll
        for (int p = 0; p < BN / RPP; ++p)
            async_load16(Bg + (size_t)(p * RPP) * KD + k0, &Bs[(rsub + p * RPP) * BK + kb]);
    };

    auto compute = [&](int buf) {
        const unsigned short* As = sm + buf * TILE;
        const unsigned short* Bs = As + BM * BK;
        #pragma unroll
        for (int ks = 0; ks < BK / 32; ++ks) {
            bf16x8 a[AM], b[AN];
            #pragma unroll
            for (int mi = 0; mi < AM; ++mi) {
                const int ar = wr * WTM + mi * 16 + (lane & 15);
                const int cg = ks * 4 + (lane >> 4);
                a[mi] = *(const bf16x8*)&As[ar * BK + ((cg ^ (ar & 7)) * 8)];
            }
            #pragma unroll
            for (int ni = 0; ni < AN; ++ni) {
                const int br = wc * WTN + ni * 16 + (lane & 15);
                const int cg = ks * 4 + (lane >> 4);
                b[ni] = *(const bf16x8*)&Bs[br * BK + ((cg ^ (br & 7)) * 8)];
            }
            #pragma unroll
            for (int mi = 0; mi < AM; ++mi)
                #pragma unroll
                for (int ni = 0; ni < AN; ++ni)
                    acc[mi][ni] = __builtin_amdgcn_mfma_f32_16x16x32_bf16(
                        b[ni], a[mi], acc[mi][ni], 0, 0, 0);
        }
    };

    #pragma unroll
    for (int p = 0; p < AHEAD; ++p) stage(p, p * BK);

    for (int it = 0; it < NIT; ++it) {
        __builtin_amdgcn_s_barrier();
        if (it + AHEAD < NIT) {
            stage((it + AHEAD) % NBUF, (it + AHEAD) * BK);
            wait_vmcnt<AHEAD * L>();
        } else if (it + 1 < NIT) {
            wait_vmcnt<L>();
        } else {
            wait_vmcnt<0>();
        }
        __builtin_amdgcn_s_barrier();
        compute(it % NBUF);
    }

    const int mrow  = bm * BM + wr * WTM + (lane & 15);
    const int ncol0 = bn * BN + wc * WTN + (lane >> 4) * 4;
    #pragma unroll
    for (int mi = 0; mi < AM; ++mi) {
        const int row = mrow + mi * 16;
        #pragma unroll
        for (int ni = 0; ni < AN; ++ni) {
            const int col = ncol0 + ni * 16;
            f32x4 v = acc[mi][ni];
            if constexpr (BIAS) {
                const f32x4 bv = *(const f32x4*)&bias[col];
                v += bv;
            }
            if constexpr (std::is_same<OUT_T, float>::value) {
                __builtin_nontemporal_store(v, (f32x4*)&C[(size_t)row * ND + col]);
            } else {
                ushort4v r;
                r[0] = f2bf(v[0]); r[1] = f2bf(v[1]);
                r[2] = f2bf(v[2]); r[3] = f2bf(v[3]);
                *(ushort4v*)&C[(size_t)row * ND + col] = r;
            }
        }
    }
}

// ---------------- K1: ALL prep (castx + weights), one launch ----------------
// blocks [0,2048):    x -> bf16 (4M elems, 2048 elems/block)
// blocks [2048,2304): WvT[e,k] = bf16(Wqkv[vrow(k), e])  (64x64 tiles)
// blocks [2304,2816): Wo -> bf16
// blocks [2816,2832): c[i] = bo[i] + sum_k Wo[i,k]*bqkv[vrow(k)]
__global__ __launch_bounds__(256) void prep_all(
    const float* __restrict__ x, const float* __restrict__ Wqkv,
    const float* __restrict__ bqkv, const float* __restrict__ Wo,
    const float* __restrict__ bo,
    unsigned short* __restrict__ x_bf, unsigned short* __restrict__ WvT,
    unsigned short* __restrict__ wo_bf, float* __restrict__ c)
{
    const int blk = blockIdx.x;
    const int t = threadIdx.x;
    if (blk < 2048) {                       // ---- cast x ----
        cast8(x, x_bf, blk * 256 + t);
    } else if (blk < 2304) {                // ---- build WvT ----
        __shared__ unsigned short tile[64][65];
        const int b = blk - 2048;
        const int eBase = (b & 15) * 64, kBase = (b >> 4) * 64;
        const int tx = t & 63, ty = t >> 6;
        #pragma unroll
        for (int r = ty; r < 64; r += 4) {
            int k = kBase + r;
            int j = ((k >> 6) * 192) + 128 + (k & 63);   // vrow(k)
            tile[r][tx] = f2bf(Wqkv[(size_t)j * EDIM + eBase + tx]);
        }
        __syncthreads();
        #pragma unroll
        for (int r = ty; r < 64; r += 4)
            WvT[(size_t)(eBase + r) * EDIM + kBase + tx] = tile[tx][r];
    } else if (blk < 2816) {                // ---- cast Wo ----
        cast8(Wo, wo_bf, (blk - 2304) * 256 + t);
    } else {                                // ---- fused bias c ----
        const int b = blk - 2816;           // 0..15
        const int wave = t >> 6, lane = t & 63;
        for (int r = 0; r < 16; ++r) {
            int row = b * 64 + wave * 16 + r;
            float s = 0.f;
            #pragma unroll
            for (int kk = 0; kk < 16; ++kk) {
                int k = kk * 64 + lane;
                int j = kk * 192 + 128 + lane;   // vrow(k)
                s += Wo[(size_t)row * EDIM + k] * bqkv[j];
            }
            #pragma unroll
            for (int off = 32; off > 0; off >>= 1) s += __shfl_down(s, off);
            if (lane == 0) c[row] = s + bo[row];
        }
    }
}

// ---------------- K2: gemm1 (M = Wo @ Wv_sub), SOLO ----------------
// 256 blocks (one per CU), 64x64 tiles, NBUF=3 counted-vmcnt. No castx
// contention: full chip + L2 bandwidth for the 4 MB weight working set.
__global__ __launch_bounds__(256, 2) void gemm1k(
    const unsigned short* __restrict__ wo_bf, const unsigned short* __restrict__ wvt,
    unsigned short* __restrict__ m_bf)
{
    __shared__ unsigned short smem[3 * (64 + 64) * 64];   // 48 KB
    gemm_bt_body<false, unsigned short, EDIM, EDIM, EDIM, 64, 64, 64, 2, 2, 3>(
        wo_bf, wvt, m_bf, nullptr, blockIdx.x, smem);
}

// ---------------- K3: out = x @ M^T + c ----------------
// 128x128 tiles, 8 waves (2x4 grid, acc[4][2]), 2-buffer counted-vmcnt
// (steady vmcnt(4)), 64 KB LDS, grid 256. T2 swizzle + float4 epilogue.
// bm-chunk XCD swizzle: each XCD's 1 MB x-panel + full 2 MB M L2-resident.
__global__ __launch_bounds__(512, 2) void gemm2(
    const unsigned short* __restrict__ x_bf, const unsigned short* __restrict__ m_bf,
    float* __restrict__ out, const float* __restrict__ cvec)
{
    __shared__ unsigned short smem[2 * (128 + 128) * 64];  // 64 KB
    gemm_bt_body<true, float, MROWS, EDIM, EDIM, 128, 128, 64, 2, 4, 2>(
        x_bf, m_bf, out, cvec, blockIdx.x, smem);
}

extern "C" void kernel_launch(void* const* d_in, const int* in_sizes, int n_in,
                              void* d_out, int out_size, void* d_ws, size_t ws_size,
                              hipStream_t stream) {
    const float* x    = (const float*)d_in[0];   // (2,2048,1024)
    const float* Wqkv = (const float*)d_in[1];   // (3072,1024)
    const float* bqkv = (const float*)d_in[2];   // (3072,)
    const float* Wo   = (const float*)d_in[3];   // (1024,1024)
    const float* bo   = (const float*)d_in[4];   // (1024,)
    float* out = (float*)d_out;                  // (2,2048,1024) f32

    char* ws = (char*)d_ws;
    unsigned short* x_bf  = (unsigned short*)(ws);                       // 8 MB
    unsigned short* wvt   = (unsigned short*)(ws + 8u  * 1024 * 1024);   // 2 MB
    unsigned short* wo_bf = (unsigned short*)(ws + 10u * 1024 * 1024);   // 2 MB
    unsigned short* m_bf  = (unsigned short*)(ws + 12u * 1024 * 1024);   // 2 MB
    float*          cvec  = (float*)(ws + 14u * 1024 * 1024);            // 4 KB

    // K1: ALL memory prep in one launch (castx || WvT || Wo-cast || cvec)
    prep_all<<<2832, 256, 0, stream>>>(x, Wqkv, bqkv, Wo, bo, x_bf, wvt, wo_bf, cvec);
    // K2: M = Wo @ Wv_sub — solo, full chip
    gemm1k<<<256, 256, 0, stream>>>(wo_bf, wvt, m_bf);
    // K3: out = x @ M^T + c (128x128, 8 waves, counted-vmcnt, T2, bm-chunk swizzle)
    gemm2<<<256, 512, 0, stream>>>(x_bf, m_bf, out, cvec);
}